// Round 3
// baseline (704.263 us; speedup 1.0000x reference)
//
#include <hip/hip_runtime.h>

// MPS classifier, MI355X gfx950.
// B=8192, N=256 sites, D=128 bond, K=2D=256, OUT=10.
// Inputs fp32, OUTPUT fp32 (reference dtype; round-2 bf16-out was the bug).
// Compute: fp16 MFMA (mfma_f32_16x16x32_f16), fp32 accumulate; A re-quantized
// to fp16 (RNE) each site. Error ~2^-12*sqrt(508) ~ 1.6e-3 rel << 2% threshold.
// Persistent: 256 WGs x 256 threads; WG g owns rows 32g..32g+31.

typedef _Float16 v8h __attribute__((ext_vector_type(8)));
typedef float v4f __attribute__((ext_vector_type(4)));

#define PI_HALF 1.5707963267948966f

union U4H8 { uint4 u; v8h h; };

__device__ __forceinline__ v4f mfma16h(uint4 a, uint4 b, v4f c){
  U4H8 ua, ub; ua.u = a; ub.u = b;
  return __builtin_amdgcn_mfma_f32_16x16x32_f16(ua.h, ub.h, c, 0, 0, 0);
}

__device__ __forceinline__ unsigned short f2h(float f){
  _Float16 h = (_Float16)f;            // v_cvt_f16_f32, RNE
  return __builtin_bit_cast(unsigned short, h);
}

// ---------------------------------------------------------------------------
// Repack mid (fp32 [254][128][2][128]) -> fp16 B-fragment layout in ws:
// wsB[site][kt][ntg][lane][j] (j=0..7 fp16, 16B/lane)
// element = M_site[k = 32*kt + 8*(lane>>4) + j][n = 16*ntg + (lane&15)]
// M_site[k][n] = mid[site*32768 + k*128 + n], k = 2l+d.  Total 16.6 MB.
// ---------------------------------------------------------------------------
__global__ __launch_bounds__(256) void repack_mid(const float* __restrict__ mid,
                                                  unsigned short* __restrict__ wsB){
  int idx = blockIdx.x * 256 + threadIdx.x;   // 0 .. 254*8*8*64-1
  int lam  = idx & 63;
  int nt   = (idx >> 6) & 7;
  int kt   = (idx >> 9) & 7;
  int site = idx >> 12;
  const float* src = mid + (size_t)site * 32768
                   + (size_t)(32*kt + 8*(lam>>4)) * 128 + 16*nt + (lam & 15);
  unsigned int p[4];
  #pragma unroll
  for (int jp = 0; jp < 4; ++jp){
    unsigned int lo = f2h(src[(2*jp)     * 128]);
    unsigned int hi = f2h(src[(2*jp + 1) * 128]);
    p[jp] = lo | (hi << 16);
  }
  ((uint4*)wsB)[idx] = make_uint4(p[0], p[1], p[2], p[3]);
}

// ---------------------------------------------------------------------------
// Main persistent kernel.
// LDS: ang[256 sites][32 rows] fp32 (32KB; ang[0..31] reused as scal[32] at
//      the end — site-0 angles only read in phase 2);
//      AfragU[mt][kt][lane][jpair] = 2*8*64*4 uints (16KB).
// A-frag element (lane,j) = A[m = 16*mt + (lane&15)][k = 32*kt + 8*(lane>>4)+j]
// ---------------------------------------------------------------------------
__global__ __launch_bounds__(256, 1) void mps_main(
    const float* __restrict__ x,               // [8192][256]
    const float* __restrict__ first,           // [2][128]
    const unsigned short* __restrict__ wsB,    // repacked mid, fp16 frags
    const float* __restrict__ lastw,           // [128][2]
    const float* __restrict__ wlin,            // [10]
    const float* __restrict__ blin,            // [10]
    float* __restrict__ out)                   // [8192][10] fp32
{
  __shared__ float ang[256*32];
  __shared__ unsigned int AfragU[2*8*64*4];
  float* scal = ang;

  const int tid  = threadIdx.x;
  const int g    = blockIdx.x;
  const int wave = tid >> 6;
  const int lane = tid & 63;
  const int r    = lane & 15;
  const int q    = lane >> 4;
  const int rowbase = g * 32;

  // ---- Phase 1: feature map (per-row min/max over 256 sites -> angles) ----
  {
    const int row = tid >> 3;           // 0..31
    const int c0  = (tid & 7) * 32;     // 32-site chunk
    const float4* xp = (const float4*)(x + (size_t)(rowbase + row) * 256 + c0);
    float xv[32];
    float vmin = 3.0e38f, vmax = -3.0e38f;
    #pragma unroll
    for (int c = 0; c < 8; ++c){
      float4 u = xp[c];
      xv[c*4+0] = u.x; xv[c*4+1] = u.y; xv[c*4+2] = u.z; xv[c*4+3] = u.w;
      vmin = fminf(vmin, fminf(fminf(u.x,u.y), fminf(u.z,u.w)));
      vmax = fmaxf(vmax, fmaxf(fmaxf(u.x,u.y), fmaxf(u.z,u.w)));
    }
    #pragma unroll
    for (int m = 1; m < 8; m <<= 1){
      vmin = fminf(vmin, __shfl_xor(vmin, m));
      vmax = fmaxf(vmax, __shfl_xor(vmax, m));
    }
    const float sc = PI_HALF / (vmax - vmin + 1e-6f);
    #pragma unroll
    for (int j = 0; j < 32; ++j)
      ang[(c0 + j)*32 + row] = (xv[j] - vmin) * sc;
  }
  __syncthreads();

  // ---- Phase 2: site-0 contraction + A frags for site 1 ----
  {
    float cc0[2][4], ss0[2][4], cc1[2][4], ss1[2][4];
    #pragma unroll
    for (int mt = 0; mt < 2; ++mt)
      #pragma unroll
      for (int reg = 0; reg < 4; ++reg){
        const int b = 16*mt + 4*q + reg;
        float a0 = ang[0*32 + b];
        float a1 = ang[1*32 + b];
        cc0[mt][reg] = __cosf(a0); ss0[mt][reg] = __sinf(a0);
        cc1[mt][reg] = __cosf(a1); ss1[mt][reg] = __sinf(a1);
      }
    #pragma unroll
    for (int nt = 0; nt < 2; ++nt){
      const int l  = 32*wave + 16*nt + r;
      const float f0 = first[l];
      const float f1 = first[128 + l];
      const int kt   = l >> 4;
      const int jp   = r & 3;
      const int lamb = (r >> 2)*16 + 4*q;
      #pragma unroll
      for (int mt = 0; mt < 2; ++mt)
        #pragma unroll
        for (int reg = 0; reg < 4; ++reg){
          float v  = f0*cc0[mt][reg] + f1*ss0[mt][reg];   // left0[b][l]
          float a0 = v * cc1[mt][reg];
          float a1 = v * ss1[mt][reg];
          AfragU[((mt*8 + kt)*64 + lamb + reg)*4 + jp] =
              (unsigned int)f2h(a0) | ((unsigned int)f2h(a1) << 16);
        }
    }
  }

  // ---- Main site loop ----
  const int ntg0 = 2*wave, ntg1 = 2*wave + 1;
  for (int i = 1; i <= 254; ++i){
    if (i == 254 && tid < 32) scal[tid] = 0.0f;
    __syncthreads();   // A frags for site i visible

    v4f acc[2][2] = {};   // [mt][nt]; C row b=16mt+4q+reg, col l=32w+16nt+r
    const unsigned short* Bp = wsB + (size_t)(i - 1) * 32768;
    #pragma unroll
    for (int kt = 0; kt < 8; ++kt){
      uint4 b0  = *(const uint4*)(Bp + ((size_t)(kt*8 + ntg0)*64 + lane)*8);
      uint4 b1  = *(const uint4*)(Bp + ((size_t)(kt*8 + ntg1)*64 + lane)*8);
      uint4 a0u = *(const uint4*)&AfragU[((0*8 + kt)*64 + lane)*4];
      uint4 a1u = *(const uint4*)&AfragU[((1*8 + kt)*64 + lane)*4];
      acc[0][0] = mfma16h(a0u, b0, acc[0][0]);
      acc[0][1] = mfma16h(a0u, b1, acc[0][1]);
      acc[1][0] = mfma16h(a1u, b0, acc[1][0]);
      acc[1][1] = mfma16h(a1u, b1, acc[1][1]);
    }
    __syncthreads();   // all waves done reading A frags of site i

    if (i < 254){
      // epilogue: A_{i+1}[b][2l+d] = C[b][l] * phi(b, i+1, d)
      float cc[2][4], ss[2][4];
      #pragma unroll
      for (int mt = 0; mt < 2; ++mt)
        #pragma unroll
        for (int reg = 0; reg < 4; ++reg){
          float a = ang[(i+1)*32 + 16*mt + 4*q + reg];
          cc[mt][reg] = __cosf(a); ss[mt][reg] = __sinf(a);
        }
      #pragma unroll
      for (int nt = 0; nt < 2; ++nt){
        const int l  = 32*wave + 16*nt + r;
        const int kt = l >> 4;
        const int jp = r & 3;
        const int lamb = (r >> 2)*16 + 4*q;
        #pragma unroll
        for (int mt = 0; mt < 2; ++mt)
          #pragma unroll
          for (int reg = 0; reg < 4; ++reg){
            float v  = acc[mt][nt][reg];
            AfragU[((mt*8 + kt)*64 + lamb + reg)*4 + jp] =
                (unsigned int)f2h(v * cc[mt][reg]) |
                ((unsigned int)f2h(v * ss[mt][reg]) << 16);
          }
      }
    } else {
      // final: scalar[b] = sum_l C[b][l]*(last[l][0]*cos + last[l][1]*sin)
      float cc[2][4], ss[2][4];
      #pragma unroll
      for (int mt = 0; mt < 2; ++mt)
        #pragma unroll
        for (int reg = 0; reg < 4; ++reg){
          float a = ang[255*32 + 16*mt + 4*q + reg];
          cc[mt][reg] = __cosf(a); ss[mt][reg] = __sinf(a);
        }
      float partial[2][4] = {};
      #pragma unroll
      for (int nt = 0; nt < 2; ++nt){
        const int l = 32*wave + 16*nt + r;
        const float g0 = lastw[2*l];
        const float g1 = lastw[2*l + 1];
        #pragma unroll
        for (int mt = 0; mt < 2; ++mt)
          #pragma unroll
          for (int reg = 0; reg < 4; ++reg)
            partial[mt][reg] += acc[mt][nt][reg] * (g0*cc[mt][reg] + g1*ss[mt][reg]);
      }
      #pragma unroll
      for (int m = 1; m < 16; m <<= 1)
        #pragma unroll
        for (int mt = 0; mt < 2; ++mt)
          #pragma unroll
          for (int reg = 0; reg < 4; ++reg)
            partial[mt][reg] += __shfl_xor(partial[mt][reg], m);
      if (r == 0){
        #pragma unroll
        for (int mt = 0; mt < 2; ++mt)
          #pragma unroll
          for (int reg = 0; reg < 4; ++reg)
            atomicAdd(&scal[16*mt + 4*q + reg], partial[mt][reg]);
      }
      __syncthreads();
      for (int t = tid; t < 320; t += 256){
        int bb = t / 10, o = t - bb*10;
        out[(size_t)(rowbase + bb)*10 + o] = scal[bb]*wlin[o] + blin[o];
      }
    }
  }
}

extern "C" void kernel_launch(void* const* d_in, const int* in_sizes, int n_in,
                              void* d_out, int out_size, void* d_ws, size_t ws_size,
                              hipStream_t stream){
  (void)in_sizes; (void)n_in; (void)out_size; (void)ws_size;
  const float* x     = (const float*)d_in[0];
  const float* first = (const float*)d_in[1];
  const float* mid   = (const float*)d_in[2];
  const float* lastw = (const float*)d_in[3];
  const float* wlin  = (const float*)d_in[4];
  const float* blin  = (const float*)d_in[5];
  float* o            = (float*)d_out;
  unsigned short* wsB = (unsigned short*)d_ws;   // 16.6 MB fp16 fragments

  hipLaunchKernelGGL(repack_mid, dim3(4064), dim3(256), 0, stream, mid, wsB);
  hipLaunchKernelGGL(mps_main,   dim3(256),  dim3(256), 0, stream,
                     x, first, wsB, lastw, wlin, blin, o);
}

// Round 4
// 405.517 us; speedup vs baseline: 1.7367x; 1.7367x over previous
//
#include <hip/hip_runtime.h>

// MPS classifier, MI355X gfx950. Round 4: overlap-oriented restructure.
// B=8192, N=256, D=128, K=2D=256, OUT=10. Inputs fp32, output fp32.
// 256 WGs x 512 threads (8 waves). Wave w: mt = w&1 (16-row strip),
// ntg-pair p = w>>1 (cols 32p..32p+31). One barrier/site (double-buffered
// A-frags), B prefetched into regs (2-unrolled ping-pong), epilogue uses
// packed-f16 phi table + in-register 4x4 transpose -> ds_write_b128.

typedef _Float16 v8h __attribute__((ext_vector_type(8)));
typedef _Float16 h2  __attribute__((ext_vector_type(2)));
typedef float    v4f __attribute__((ext_vector_type(4)));

#define PI_HALF 1.5707963267948966f

union U4H8 { uint4 u; v8h h; };

__device__ __forceinline__ v4f mfma16h(uint4 a, uint4 b, v4f c){
  U4H8 ua, ub; ua.u = a; ub.u = b;
  return __builtin_amdgcn_mfma_f32_16x16x32_f16(ua.h, ub.h, c, 0, 0, 0);
}
__device__ __forceinline__ unsigned short f2h_u(float f){
  _Float16 h = (_Float16)f;            // v_cvt_f16_f32, RNE
  return __builtin_bit_cast(unsigned short, h);
}
__device__ __forceinline__ unsigned pack_cs(float c, float s){
  h2 p; p[0] = (_Float16)c; p[1] = (_Float16)s;
  return __builtin_bit_cast(unsigned, p);
}
// u = (v,v) * packed(cos,sin)  -> packed f16 pair (v*cos, v*sin)
__device__ __forceinline__ unsigned mul_phi(float v, unsigned phiu){
  _Float16 vh = (_Float16)v;
  h2 vv; vv[0] = vh; vv[1] = vh;
  h2 ph = __builtin_bit_cast(h2, phiu);
  h2 r = vv * ph;                      // v_pk_mul_f16, RNE
  return __builtin_bit_cast(unsigned, r);
}

// 4x4 transpose over (lane&3, reg) within each quad of lanes.
// out f[r] @ lane t  =  in u[t-th reg] @ lane r   (i.e. f[r] = u[r][t]).
__device__ __forceinline__ void xpose4(unsigned u0, unsigned u1, unsigned u2, unsigned u3,
                                       unsigned &f0, unsigned &f1, unsigned &f2, unsigned &f3,
                                       int t){
  unsigned q0 = __shfl_xor(u0,1), q1 = __shfl_xor(u1,1);
  unsigned q2 = __shfl_xor(u2,1), q3 = __shfl_xor(u3,1);
  bool b0 = (t & 1);
  unsigned h0 = b0 ? q1 : u0,  h1 = b0 ? u1 : q0;
  unsigned h2_ = b0 ? q3 : u2, h3 = b0 ? u3 : q2;
  unsigned r0 = __shfl_xor(h0,2), r1 = __shfl_xor(h1,2);
  unsigned r2 = __shfl_xor(h2_,2), r3 = __shfl_xor(h3,2);
  bool b1 = (t & 2);
  f0 = b1 ? r2 : h0;
  f1 = b1 ? r3 : h1;
  f2 = b1 ? h2_ : r0;
  f3 = b1 ? h3 : r1;
}

// ---------------------------------------------------------------------------
// Repack mid (fp32 [254][128][2][128]) -> fp16 B-fragment layout (16.6 MB):
// wsB[site][kt][ntg][lane][j]: element = M_site[k=32kt+8(lane>>4)+j][n=16ntg+(lane&15)]
// ---------------------------------------------------------------------------
__global__ __launch_bounds__(256) void repack_mid(const float* __restrict__ mid,
                                                  unsigned short* __restrict__ wsB){
  int idx = blockIdx.x * 256 + threadIdx.x;
  int lam  = idx & 63;
  int nt   = (idx >> 6) & 7;
  int kt   = (idx >> 9) & 7;
  int site = idx >> 12;
  const float* src = mid + (size_t)site * 32768
                   + (size_t)(32*kt + 8*(lam>>4)) * 128 + 16*nt + (lam & 15);
  unsigned p[4];
  #pragma unroll
  for (int jp = 0; jp < 4; ++jp){
    unsigned lo = f2h_u(src[(2*jp)     * 128]);
    unsigned hi = f2h_u(src[(2*jp + 1) * 128]);
    p[jp] = lo | (hi << 16);
  }
  ((uint4*)wsB)[idx] = make_uint4(p[0], p[1], p[2], p[3]);
}

// ---------------------------------------------------------------------------
// Main persistent kernel. LDS: phi[256][32] packed f16 (cos,sin) = 32 KB;
// AfragU[2 buf][2 mt][8 kt][64 lane][4 jp] = 2*16 KB. scal[32] aliases buf1.
// A-frag: lane L holds A[m=16mt+(L&15)][k=32kt+8(L>>4)+j], j=2jp+d.
// ---------------------------------------------------------------------------
__global__ __launch_bounds__(512, 2) void mps_main(
    const float* __restrict__ x,               // [8192][256]
    const float* __restrict__ first,           // [2][128]
    const unsigned short* __restrict__ wsB,    // repacked mid, fp16 frags
    const float* __restrict__ lastw,           // [128][2]
    const float* __restrict__ wlin,            // [10]
    const float* __restrict__ blin,            // [10]
    float* __restrict__ out)                   // [8192][10]
{
  __shared__ unsigned phiT[256*32];
  __shared__ unsigned AfragU[2*2*8*64*4];
  float* scal = (float*)&AfragU[4096];   // buf1 head; free during site 254

  const int tid  = threadIdx.x;
  const int g    = blockIdx.x;
  const int wave = tid >> 6;
  const int lane = tid & 63;
  const int r    = lane & 15;
  const int q    = lane >> 4;
  const int mt   = wave & 1;
  const int p    = wave >> 1;            // ntg pair: {2p, 2p+1}
  const int rowbase = g * 32;

  // ---- Phase 1: feature map -> packed f16 (cos,sin) table ----
  {
    const int row = tid >> 4;            // 0..31
    const int c0  = (tid & 15) * 16;     // 16-site chunk
    const float4* xp = (const float4*)(x + (size_t)(rowbase + row) * 256 + c0);
    float xv[16];
    float vmin = 3.0e38f, vmax = -3.0e38f;
    #pragma unroll
    for (int c = 0; c < 4; ++c){
      float4 u = xp[c];
      xv[c*4+0] = u.x; xv[c*4+1] = u.y; xv[c*4+2] = u.z; xv[c*4+3] = u.w;
      vmin = fminf(vmin, fminf(fminf(u.x,u.y), fminf(u.z,u.w)));
      vmax = fmaxf(vmax, fmaxf(fmaxf(u.x,u.y), fmaxf(u.z,u.w)));
    }
    #pragma unroll
    for (int m = 1; m < 16; m <<= 1){
      vmin = fminf(vmin, __shfl_xor(vmin, m));
      vmax = fmaxf(vmax, __shfl_xor(vmax, m));
    }
    const float sc = PI_HALF / (vmax - vmin + 1e-6f);
    #pragma unroll
    for (int j = 0; j < 16; ++j){
      float a = (xv[j] - vmin) * sc;
      phiT[(c0 + j)*32 + row] = pack_cs(__cosf(a), __sinf(a));
    }
  }
  __syncthreads();

  // ---- Phase 2: site-0 contraction -> A frags for site 1 (buf 1) ----
  {
    const int m = 16*mt + r;
    h2 ph0 = __builtin_bit_cast(h2, phiT[0*32 + m]);
    const float c0 = (float)ph0[0], s0 = (float)ph0[1];
    const unsigned phi1 = phiT[1*32 + m];
    #pragma unroll
    for (int ktb = 0; ktb < 2; ++ktb){
      const int kt = 2*p + ktb;
      unsigned u[4];
      #pragma unroll
      for (int jp = 0; jp < 4; ++jp){
        const int l = 16*kt + 4*q + jp;
        float v = first[l]*c0 + first[128 + l]*s0;   // left0[b=m][l]
        u[jp] = mul_phi(v, phi1);
      }
      *(uint4*)&AfragU[4096 + ((mt*8 + kt)*64 + lane)*4] =
          make_uint4(u[0], u[1], u[2], u[3]);
    }
  }

  // ---- B prefetch for site 1 ----
  uint4 Breg0[16], Breg1[16];
  {
    const uint4* bp = (const uint4*)wsB;   // site-1 weights at offset 0
    #pragma unroll
    for (int kt = 0; kt < 8; ++kt){
      Breg0[kt*2+0] = bp[((kt*8 + 2*p    )*64) + lane];
      Breg0[kt*2+1] = bp[((kt*8 + 2*p + 1)*64) + lane];
    }
  }

  const int t3 = lane & 3;   // transpose quad index

  // ---- Site body (one barrier per site) ----
  auto body = [&](int site, uint4 (&Bcur)[16], uint4 (&Bnxt)[16]){
    __syncthreads();   // A frags for `site` visible; prev buf reads done

    if (site == 254 && tid < 32) scal[tid] = 0.0f;   // buf1 idle at 254

    // prefetch B for site+1 (clamped; values unused at site 254)
    {
      const int soff = (site <= 253) ? site : 0;
      const uint4* bp = (const uint4*)(wsB + (size_t)soff * 32768);
      #pragma unroll
      for (int kt = 0; kt < 8; ++kt){
        Bnxt[kt*2+0] = bp[((kt*8 + 2*p    )*64) + lane];
        Bnxt[kt*2+1] = bp[((kt*8 + 2*p + 1)*64) + lane];
      }
    }

    // MFMA: C[16mt.., 32p..] += A(site) * B(site)
    v4f acc[2] = {};   // [ntb]; C row = 16mt+4q+reg, col = 16(2p+ntb)+r
    const unsigned* Abuf = &AfragU[(site & 1) * 4096];
    #pragma unroll
    for (int kt = 0; kt < 8; ++kt){
      uint4 a = *(const uint4*)&Abuf[((mt*8 + kt)*64 + lane)*4];
      acc[0] = mfma16h(a, Bcur[kt*2+0], acc[0]);
      acc[1] = mfma16h(a, Bcur[kt*2+1], acc[1]);
    }

    if (site < 254){
      // epilogue: A_{site+1}[b][2l+d] = C[b][l] * phi(b, site+1, d)
      uint4 phiu = *(const uint4*)&phiT[(site+1)*32 + 16*mt + 4*q]; // 4 rows
      const unsigned pr[4] = {phiu.x, phiu.y, phiu.z, phiu.w};
      unsigned* Wbuf = &AfragU[((site+1) & 1) * 4096];
      const int lamf = 16*((lane>>2)&3) + 4*(lane>>4) + t3;
      #pragma unroll
      for (int ntb = 0; ntb < 2; ++ntb){
        unsigned u[4];
        #pragma unroll
        for (int reg = 0; reg < 4; ++reg)
          u[reg] = mul_phi(acc[ntb][reg], pr[reg]);
        unsigned f0,f1,f2,f3;
        xpose4(u[0],u[1],u[2],u[3], f0,f1,f2,f3, t3);
        *(uint4*)&Wbuf[((mt*8 + (2*p + ntb))*64 + lamf)*4] =
            make_uint4(f0,f1,f2,f3);
      }
    } else {
      // final: scalar[b] = sum_l C[b][l]*(last[l][0]*cos_b + last[l][1]*sin_b)
      uint4 phiu = *(const uint4*)&phiT[255*32 + 16*mt + 4*q];
      const unsigned pr[4] = {phiu.x, phiu.y, phiu.z, phiu.w};
      float part[4] = {};
      #pragma unroll
      for (int ntb = 0; ntb < 2; ++ntb){
        const int l = 16*(2*p + ntb) + r;
        const float g0 = lastw[2*l];
        const float g1 = lastw[2*l + 1];
        #pragma unroll
        for (int reg = 0; reg < 4; ++reg){
          h2 ph = __builtin_bit_cast(h2, pr[reg]);
          float coef = g0*(float)ph[0] + g1*(float)ph[1];
          part[reg] += acc[ntb][reg] * coef;
        }
      }
      #pragma unroll
      for (int m = 1; m < 16; m <<= 1)
        #pragma unroll
        for (int reg = 0; reg < 4; ++reg)
          part[reg] += __shfl_xor(part[reg], m);
      __syncthreads();            // scal zeroing visible
      if (r == 0){
        #pragma unroll
        for (int reg = 0; reg < 4; ++reg)
          atomicAdd(&scal[16*mt + 4*q + reg], part[reg]);
      }
      __syncthreads();
      for (int t = tid; t < 320; t += 512){
        int bb = t / 10, o = t - bb*10;
        out[(size_t)(rowbase + bb)*10 + o] = scal[bb]*wlin[o] + blin[o];
      }
    }
  };

  #pragma unroll 1
  for (int i = 1; i <= 253; i += 2){
    body(i,     Breg0, Breg1);
    body(i + 1, Breg1, Breg0);
  }
}

extern "C" void kernel_launch(void* const* d_in, const int* in_sizes, int n_in,
                              void* d_out, int out_size, void* d_ws, size_t ws_size,
                              hipStream_t stream){
  (void)in_sizes; (void)n_in; (void)out_size; (void)ws_size;
  const float* x     = (const float*)d_in[0];
  const float* first = (const float*)d_in[1];
  const float* mid   = (const float*)d_in[2];
  const float* lastw = (const float*)d_in[3];
  const float* wlin  = (const float*)d_in[4];
  const float* blin  = (const float*)d_in[5];
  float* o            = (float*)d_out;
  unsigned short* wsB = (unsigned short*)d_ws;   // 16.6 MB fp16 fragments

  hipLaunchKernelGGL(repack_mid, dim3(4064), dim3(256), 0, stream, mid, wsB);
  hipLaunchKernelGGL(mps_main,   dim3(256),  dim3(512), 0, stream,
                     x, first, wsB, lastw, wlin, blin, o);
}

// Round 6
// 328.312 us; speedup vs baseline: 2.1451x; 1.2352x over previous
//
#include <hip/hip_runtime.h>

// MPS classifier, MI355X gfx950. Round 6: r5 tiling with the B site-stride
// bug fixed (uint4 site stride is 4096, not 2048 — r5's only defect).
// B=8192, N=256, D=128, K=2D=256, OUT=10. fp32 in, fp32 out, fp16 MFMA.
// 256 WGs x 256 threads (4 waves). Wave w owns C[0..32)[32w..32w+32)
// (both mt strips) -> B loaded once per CU: 64 KB/site/CU (L2-bound floor).
// One barrier/site, double-buffered A-frags in LDS, B reg-prefetch (ping-pong),
// DPP quad-perm transpose (VALU pipe, not LDS), phiT stride-36 (bank-safe).

typedef _Float16 v8h __attribute__((ext_vector_type(8)));
typedef _Float16 h2  __attribute__((ext_vector_type(2)));
typedef float    v4f __attribute__((ext_vector_type(4)));

#define PI_HALF 1.5707963267948966f
#define SITE_U4 4096   // uint4 per site in wsB: 8 kt * 8 ntg * 64 lanes

union U4H8 { uint4 u; v8h h; };

__device__ __forceinline__ v4f mfma16h(uint4 a, uint4 b, v4f c){
  U4H8 ua, ub; ua.u = a; ub.u = b;
  return __builtin_amdgcn_mfma_f32_16x16x32_f16(ua.h, ub.h, c, 0, 0, 0);
}
__device__ __forceinline__ unsigned pack2h(float lo, float hi){
  h2 p; p[0] = (_Float16)lo; p[1] = (_Float16)hi;
  return __builtin_bit_cast(unsigned, p);
}
// (v*cos, v*sin) packed f16
__device__ __forceinline__ unsigned mul_phi(float v, unsigned phiu){
  _Float16 vh = (_Float16)v;
  h2 vv; vv[0] = vh; vv[1] = vh;
  h2 ph = __builtin_bit_cast(h2, phiu);
  h2 r = vv * ph;
  return __builtin_bit_cast(unsigned, r);
}

// lane^1 / lane^2 within quads via DPP quad_perm — VALU pipe, no LDS traffic.
__device__ __forceinline__ unsigned dpp_xor1(unsigned x){
  return (unsigned)__builtin_amdgcn_mov_dpp((int)x, 0xB1, 0xF, 0xF, true);
}
__device__ __forceinline__ unsigned dpp_xor2(unsigned x){
  return (unsigned)__builtin_amdgcn_mov_dpp((int)x, 0x4E, 0xF, 0xF, true);
}
// 4x4 transpose within lane quads; t = lane&3. out f[a]@quadlane t = u[t]@quadlane a.
__device__ __forceinline__ void xpose4(const unsigned u[4], unsigned f[4], int t){
  unsigned q0 = dpp_xor1(u[0]), q1 = dpp_xor1(u[1]);
  unsigned q2 = dpp_xor1(u[2]), q3 = dpp_xor1(u[3]);
  bool b0 = (t & 1);
  unsigned h0 = b0 ? q1 : u[0];
  unsigned h1 = b0 ? u[1] : q0;
  unsigned h2_ = b0 ? q3 : u[2];
  unsigned h3 = b0 ? u[3] : q2;
  unsigned r0 = dpp_xor2(h0), r1 = dpp_xor2(h1);
  unsigned r2 = dpp_xor2(h2_), r3 = dpp_xor2(h3);
  bool b1 = (t & 2);
  f[0] = b1 ? r2 : h0;
  f[1] = b1 ? r3 : h1;
  f[2] = b1 ? h2_ : r0;
  f[3] = b1 ? h3 : r1;
}

// ---------------------------------------------------------------------------
// Repack mid (fp32 [254][128][2][128]) -> fp16 B-fragment layout (16.6 MB):
// wsB[site][kt][ntg][lane] uint4: element (lane,j) =
//   M_site[k=32kt+8(lane>>4)+j][n=16ntg+(lane&15)], k = 2l+d.
// float4 loads (fully coalesced), 4 transposed uint4 stores per thread.
// ---------------------------------------------------------------------------
__global__ __launch_bounds__(256) void repack_mid(const float* __restrict__ mid,
                                                  unsigned short* __restrict__ wsB){
  int idx  = blockIdx.x * 256 + threadIdx.x;   // 0 .. 254*8*8*16-1
  int lg   = idx & 15;          // q = lg>>2, n-sub = lg&3
  int nt   = (idx >> 4) & 7;
  int kt   = (idx >> 7) & 7;
  int site = idx >> 10;
  int q    = lg >> 2;
  int n0   = 16*nt + 4*(lg & 3);
  const float* src = mid + (size_t)site*32768 + (size_t)(32*kt + 8*q)*128 + n0;
  float Lv[4][4], Hv[4][4];
  #pragma unroll
  for (int jp = 0; jp < 4; ++jp){
    float4 a = *(const float4*)(src + (size_t)(2*jp)*128);
    float4 b = *(const float4*)(src + (size_t)(2*jp+1)*128);
    Lv[jp][0]=a.x; Lv[jp][1]=a.y; Lv[jp][2]=a.z; Lv[jp][3]=a.w;
    Hv[jp][0]=b.x; Hv[jp][1]=b.y; Hv[jp][2]=b.z; Hv[jp][3]=b.w;
  }
  uint4* dst = (uint4*)wsB + (((size_t)(site*8 + kt)*8 + nt)*64 + 16*q + 4*(lg&3));
  #pragma unroll
  for (int t = 0; t < 4; ++t){
    uint4 o;
    o.x = pack2h(Lv[0][t], Hv[0][t]);
    o.y = pack2h(Lv[1][t], Hv[1][t]);
    o.z = pack2h(Lv[2][t], Hv[2][t]);
    o.w = pack2h(Lv[3][t], Hv[3][t]);
    dst[t] = o;
  }
}

// ---------------------------------------------------------------------------
// Main persistent kernel. LDS: phiT[256 sites][36] packed f16 (cos,sin), 36 KB
// (stride 36 words: 16B-aligned rows, bank-spread); AfragU 2 bufs x 16 KB;
// scal[32]. A-frag: lane L holds A[m=16mt+(L&15)][k=32kt+8(L>>4)+j].
// ---------------------------------------------------------------------------
__global__ __launch_bounds__(256, 1) void mps_main(
    const float* __restrict__ x,               // [8192][256]
    const float* __restrict__ first,           // [2][128]
    const unsigned short* __restrict__ wsB,    // repacked mid, fp16 frags
    const float* __restrict__ lastw,           // [128][2]
    const float* __restrict__ wlin,            // [10]
    const float* __restrict__ blin,            // [10]
    float* __restrict__ out)                   // [8192][10]
{
  __shared__ unsigned phiT[256*36];
  __shared__ unsigned AfragU[2*2*8*64*4];
  __shared__ float scal[32];

  const int tid  = threadIdx.x;
  const int g    = blockIdx.x;
  const int w    = tid >> 6;             // wave 0..3: cols [32w, 32w+32)
  const int lane = tid & 63;
  const int r    = lane & 15;
  const int q    = lane >> 4;
  const int rowbase = g * 32;

  // ---- Phase 1: feature map -> packed f16 (cos,sin) table ----
  {
    const int row = tid >> 3;            // 0..31
    const int c0  = (tid & 7) * 32;      // 32-site chunk
    const float4* xp = (const float4*)(x + (size_t)(rowbase + row) * 256 + c0);
    float xv[32];
    float vmin = 3.0e38f, vmax = -3.0e38f;
    #pragma unroll
    for (int c = 0; c < 8; ++c){
      float4 u = xp[c];
      xv[c*4+0] = u.x; xv[c*4+1] = u.y; xv[c*4+2] = u.z; xv[c*4+3] = u.w;
      vmin = fminf(vmin, fminf(fminf(u.x,u.y), fminf(u.z,u.w)));
      vmax = fmaxf(vmax, fmaxf(fmaxf(u.x,u.y), fmaxf(u.z,u.w)));
    }
    #pragma unroll
    for (int m = 1; m < 8; m <<= 1){
      vmin = fminf(vmin, __shfl_xor(vmin, m));
      vmax = fmaxf(vmax, __shfl_xor(vmax, m));
    }
    const float sc = PI_HALF / (vmax - vmin + 1e-6f);
    #pragma unroll
    for (int j = 0; j < 32; ++j){
      float a = (xv[j] - vmin) * sc;
      phiT[(c0 + j)*36 + row] = pack2h(__cosf(a), __sinf(a));
    }
  }
  __syncthreads();

  // ---- Phase 2: site-0 contraction -> A frags for site 1 (buf 1) ----
  {
    #pragma unroll
    for (int mt = 0; mt < 2; ++mt){
      const int m = 16*mt + r;
      h2 ph0 = __builtin_bit_cast(h2, phiT[0*36 + m]);
      const float c0v = (float)ph0[0], s0v = (float)ph0[1];
      const unsigned phi1 = phiT[1*36 + m];
      #pragma unroll
      for (int ktb = 0; ktb < 2; ++ktb){
        const int kt = 2*w + ktb;
        unsigned u[4];
        #pragma unroll
        for (int jp = 0; jp < 4; ++jp){
          const int l = 16*kt + 4*q + jp;
          float v = first[l]*c0v + first[128 + l]*s0v;   // left0[b=m][l]
          u[jp] = mul_phi(v, phi1);
        }
        *(uint4*)&AfragU[4096 + ((mt*8 + kt)*64 + lane)*4] =
            make_uint4(u[0], u[1], u[2], u[3]);
      }
    }
  }

  // ---- B prefetch for site 1 (weights index 0) ----
  uint4 Breg0[16], Breg1[16];
  {
    const uint4* bp = (const uint4*)wsB;
    #pragma unroll
    for (int kt = 0; kt < 8; ++kt)
      #pragma unroll
      for (int nb = 0; nb < 2; ++nb)
        Breg0[kt*2+nb] = bp[(size_t)(kt*8 + 2*w + nb)*64 + lane];
  }

  const int t3   = lane & 3;
  const int lamf = 16*((lane>>2)&3) + 4*(lane>>4) + t3;

  // ---- Site body (one barrier per site) ----
  auto body = [&](int site, uint4 (&Bcur)[16], uint4 (&Bnxt)[16]){
    __syncthreads();   // A frags for `site` visible; prev-buf reads done

    // prefetch B for site+1 (weights index `site`; clamped, unused at 254)
    {
      const int soff = (site <= 253) ? site : 0;
      const uint4* bp = (const uint4*)wsB + (size_t)soff * SITE_U4;
      #pragma unroll
      for (int kt = 0; kt < 8; ++kt)
        #pragma unroll
        for (int nb = 0; nb < 2; ++nb)
          Bnxt[kt*2+nb] = bp[(size_t)(kt*8 + 2*w + nb)*64 + lane];
    }

    // MFMA: C[0..32)[32w..32w+32) += A(site) * B(site)
    v4f acc[2][2] = {};   // [mt][nb]; row=16mt+4q+reg, col=16(2w+nb)+r
    const unsigned* Abuf = &AfragU[(site & 1) * 4096];
    #pragma unroll
    for (int kt = 0; kt < 8; ++kt){
      uint4 a0 = *(const uint4*)&Abuf[((0*8 + kt)*64 + lane)*4];
      uint4 a1 = *(const uint4*)&Abuf[((1*8 + kt)*64 + lane)*4];
      acc[0][0] = mfma16h(a0, Bcur[kt*2+0], acc[0][0]);
      acc[0][1] = mfma16h(a0, Bcur[kt*2+1], acc[0][1]);
      acc[1][0] = mfma16h(a1, Bcur[kt*2+0], acc[1][0]);
      acc[1][1] = mfma16h(a1, Bcur[kt*2+1], acc[1][1]);
    }

    if (site < 254){
      // epilogue: A_{site+1}[b][2l+d] = C[b][l] * phi(b, site+1, d)
      unsigned* Wbuf = &AfragU[((site+1) & 1) * 4096];
      #pragma unroll
      for (int mt = 0; mt < 2; ++mt){
        uint4 phiu = *(const uint4*)&phiT[(site+1)*36 + 16*mt + 4*q];
        const unsigned pr[4] = {phiu.x, phiu.y, phiu.z, phiu.w};
        #pragma unroll
        for (int nb = 0; nb < 2; ++nb){
          unsigned u[4], f[4];
          #pragma unroll
          for (int reg = 0; reg < 4; ++reg)
            u[reg] = mul_phi(acc[mt][nb][reg], pr[reg]);
          xpose4(u, f, t3);
          *(uint4*)&Wbuf[((mt*8 + (2*w + nb))*64 + lamf)*4] =
              make_uint4(f[0], f[1], f[2], f[3]);
        }
      }
    } else {
      // final: scalar[b] = sum_l C[b][l]*(last[l][0]*cos_b + last[l][1]*sin_b)
      float part[2][4] = {};
      #pragma unroll
      for (int mt = 0; mt < 2; ++mt){
        uint4 phiu = *(const uint4*)&phiT[255*36 + 16*mt + 4*q];
        const unsigned pr[4] = {phiu.x, phiu.y, phiu.z, phiu.w};
        #pragma unroll
        for (int nb = 0; nb < 2; ++nb){
          const int l = 16*(2*w + nb) + r;
          const float g0 = lastw[2*l];
          const float g1 = lastw[2*l + 1];
          #pragma unroll
          for (int reg = 0; reg < 4; ++reg){
            h2 ph = __builtin_bit_cast(h2, pr[reg]);
            float coef = g0*(float)ph[0] + g1*(float)ph[1];
            part[mt][reg] += acc[mt][nb][reg] * coef;
          }
        }
      }
      #pragma unroll
      for (int m = 1; m < 16; m <<= 1)
        #pragma unroll
        for (int mt = 0; mt < 2; ++mt)
          #pragma unroll
          for (int reg = 0; reg < 4; ++reg)
            part[mt][reg] += __shfl_xor(part[mt][reg], m);
      if (tid < 32) scal[tid] = 0.0f;
      __syncthreads();
      if (r == 0){
        #pragma unroll
        for (int mt = 0; mt < 2; ++mt)
          #pragma unroll
          for (int reg = 0; reg < 4; ++reg)
            atomicAdd(&scal[16*mt + 4*q + reg], part[mt][reg]);
      }
      __syncthreads();
      for (int t = tid; t < 320; t += 256){
        int bb = t / 10, o = t - bb*10;
        out[(size_t)(rowbase + bb)*10 + o] = scal[bb]*wlin[o] + blin[o];
      }
    }
  };

  #pragma unroll 1
  for (int i = 1; i <= 253; i += 2){
    body(i,     Breg0, Breg1);
    body(i + 1, Breg1, Breg0);
  }
}

extern "C" void kernel_launch(void* const* d_in, const int* in_sizes, int n_in,
                              void* d_out, int out_size, void* d_ws, size_t ws_size,
                              hipStream_t stream){
  (void)in_sizes; (void)n_in; (void)out_size; (void)ws_size;
  const float* x     = (const float*)d_in[0];
  const float* first = (const float*)d_in[1];
  const float* mid   = (const float*)d_in[2];
  const float* lastw = (const float*)d_in[3];
  const float* wlin  = (const float*)d_in[4];
  const float* blin  = (const float*)d_in[5];
  float* o            = (float*)d_out;
  unsigned short* wsB = (unsigned short*)d_ws;   // 16.6 MB fp16 fragments

  hipLaunchKernelGGL(repack_mid, dim3(1016), dim3(256), 0, stream, mid, wsB);
  hipLaunchKernelGGL(mps_main,   dim3(256),  dim3(256), 0, stream,
                     x, first, wsB, lastw, wlin, blin, o);
}